// Round 1
// baseline (171.610 us; speedup 1.0000x reference)
//
#include <hip/hip_runtime.h>
#include <float.h>
#include <math.h>

// Problem constants (from reference)
constexpr int NP = 30000;
constexpr int M  = 32;
constexpr float VXc = 0.2f, VYc = 0.2f, VZc = 4.0f;
constexpr float XOFFc = 0.1f, YOFFc = -39.9f, ZOFFc = -1.0f;

// ---------------------------------------------------------------------------
// Helpers
// ---------------------------------------------------------------------------
__device__ __forceinline__ float wavesum64(float v) {
#pragma unroll
    for (int m = 32; m >= 1; m >>= 1) v += __shfl_xor(v, m, 64);
    return v;
}

// ---------------------------------------------------------------------------
// Kernel 1: global second-moment stats for BatchNorm.
// x = feats @ W where feats has 7 unique columns (f_center repeated), so
// mean_c = (S1 . W'_c)/NM and E[x^2]_c = W'_c^T S2 W'_c / NM. We reduce
// S1[7] and the 28 unique entries of the symmetric 7x7 S2 in fp32 per-thread
// / per-block, accumulating globally in double (magnitudes up to ~2e6 per
// term; double atomics avoid cancellation in var = E[x^2]-mean^2).
// ---------------------------------------------------------------------------
__global__ __launch_bounds__(256) void stats_kernel(
    const float4* __restrict__ fp,        // (N*M) xyzw
    const int*    __restrict__ num_points,
    const int*    __restrict__ coors,     // (N,4)
    double*       __restrict__ Sout)      // 35 doubles, pre-zeroed
{
    float S[35];
#pragma unroll
    for (int k = 0; k < 35; ++k) S[k] = 0.f;

    int n = blockIdx.x * blockDim.x + threadIdx.x;
    if (n < NP) {
        int npts = num_points[n];
        int c1 = coors[4 * n + 1], c2 = coors[4 * n + 2], c3 = coors[4 * n + 3];
        float cx = (float)c3 * VXc + XOFFc;
        float cy = (float)c2 * VYc + YOFFc;
        float cz = (float)c1 * VZc + ZOFFc;
        const float4* p = fp + (size_t)n * M;

        // points_mean uses the sum over ALL M points / npts (ref semantics)
        float sx = 0.f, sy = 0.f, sz = 0.f;
        for (int i = 0; i < M; ++i) { float4 f = p[i]; sx += f.x; sy += f.y; sz += f.z; }
        float inv = 1.f / (float)npts;
        float mx = sx * inv, my = sy * inv, mz = sz * inv;

        // masked rows (i >= npts) contribute exact zeros -> skip them
        for (int i = 0; i < npts; ++i) {
            float4 f = p[i];
            float u[7] = { f.x - cx, f.y - cy, f.z - cz, f.w,
                           f.x - mx, f.y - my, f.z - mz };
#pragma unroll
            for (int k = 0; k < 7; ++k) S[k] += u[k];
            int idx = 7;
#pragma unroll
            for (int k = 0; k < 7; ++k)
#pragma unroll
                for (int l = k; l < 7; ++l)
                    S[idx++] += u[k] * u[l];
        }
    }

    // wave reduce, then cross-wave via LDS, then 35 double atomics per block
#pragma unroll
    for (int k = 0; k < 35; ++k) S[k] = wavesum64(S[k]);

    __shared__ float part[4][35];
    int wid = threadIdx.x >> 6, ln = threadIdx.x & 63;
    if (ln == 0) {
#pragma unroll
        for (int k = 0; k < 35; ++k) part[wid][k] = S[k];
    }
    __syncthreads();
    if (threadIdx.x < 35) {
        float t = part[0][threadIdx.x] + part[1][threadIdx.x] +
                  part[2][threadIdx.x] + part[3][threadIdx.x];
        atomicAdd(&Sout[threadIdx.x], (double)t);
    }
}

// ---------------------------------------------------------------------------
// Kernel 2: fold BN into per-channel affine y = a*x + b (double precision).
// a = gamma * rsqrt(var+eps), b = beta - mean*a.
// ---------------------------------------------------------------------------
__global__ __launch_bounds__(64) void affine_kernel(
    const double* __restrict__ S,       // 35
    const float*  __restrict__ pfn_w,   // (10,64)
    const float*  __restrict__ gamma,
    const float*  __restrict__ beta,
    float*        __restrict__ AB)      // A[64] then B[64]
{
    int c = threadIdx.x;
    double w7[7];
    w7[0] = (double)pfn_w[0 * 64 + c] + (double)pfn_w[7 * 64 + c];
    w7[1] = (double)pfn_w[1 * 64 + c] + (double)pfn_w[8 * 64 + c];
    w7[2] = (double)pfn_w[2 * 64 + c] + (double)pfn_w[9 * 64 + c];
    w7[3] = (double)pfn_w[3 * 64 + c];
    w7[4] = (double)pfn_w[4 * 64 + c];
    w7[5] = (double)pfn_w[5 * 64 + c];
    w7[6] = (double)pfn_w[6 * 64 + c];

    const double invNM = 1.0 / ((double)NP * (double)M);
    double mean = 0.0;
#pragma unroll
    for (int k = 0; k < 7; ++k) mean += S[k] * w7[k];
    mean *= invNM;

    double ex2 = 0.0;
    int idx = 7;
#pragma unroll
    for (int k = 0; k < 7; ++k)
#pragma unroll
        for (int l = k; l < 7; ++l) {
            double t = S[idx++] * w7[k] * w7[l];
            ex2 += (k == l) ? t : 2.0 * t;
        }
    ex2 *= invNM;

    double var = ex2 - mean * mean;
    double a = (double)gamma[c] / sqrt(var + 1e-3);
    AB[c]      = (float)a;
    AB[64 + c] = (float)((double)beta[c] - mean * a);
}

// ---------------------------------------------------------------------------
// Kernel 3: main. One 64-thread block (1 wave) per pillar.
// Lanes duplicate point work across halves (i = lane & 31) so width-32
// shuffles need no masking; step C uses all 64 lanes as channels.
// Rank-1 attention: scores[h,i,j] = q_ih * k_jh, so the softmax row max is
// q_ih * (q_ih>=0 ? max_j k_jh : min_j k_jh) -> single exp pass.
// ---------------------------------------------------------------------------
__global__ __launch_bounds__(64) void main_kernel(
    const float4* __restrict__ fp,
    const int*    __restrict__ num_points,
    const int*    __restrict__ coors,
    const float*  __restrict__ pfn_w,
    const float*  __restrict__ AB,
    const float*  __restrict__ wq, const float* __restrict__ wk,
    const float*  __restrict__ wv, const float* __restrict__ wo,
    const float*  __restrict__ bq, const float* __restrict__ bk,
    const float*  __restrict__ bv, const float* __restrict__ bo,
    float*        __restrict__ out)
{
    const int n    = blockIdx.x;
    const int lane = threadIdx.x;   // 0..63
    const int i    = lane & 31;

    __shared__ float k_s[3][32];
    __shared__ float v_s[3][32];
    __shared__ float u_s[32][7];
    __shared__ float r_s[32];

    const float4 f = fp[(size_t)n * M + i];

    // q/k/v for this point (weights are uniform -> scalar loads)
    float q[3], kk[3], vv[3];
#pragma unroll
    for (int h = 0; h < 3; ++h) {
        q[h]  = f.x * wq[0 * 3 + h] + f.y * wq[1 * 3 + h] + f.z * wq[2 * 3 + h] + bq[h];
        kk[h] = f.x * wk[0 * 3 + h] + f.y * wk[1 * 3 + h] + f.z * wk[2 * 3 + h] + bk[h];
        vv[h] = f.x * wv[0 * 3 + h] + f.y * wv[1 * 3 + h] + f.z * wv[2 * 3 + h] + bv[h];
    }
    if (lane < 32) {
#pragma unroll
        for (int h = 0; h < 3; ++h) { k_s[h][i] = kk[h]; v_s[h][i] = vv[h]; }
    }

    // width-32 butterfly reductions: xyz sum + per-head k max/min
    float sx = f.x, sy = f.y, sz = f.z;
    float kmx[3], kmn[3];
#pragma unroll
    for (int h = 0; h < 3; ++h) { kmx[h] = kk[h]; kmn[h] = kk[h]; }
#pragma unroll
    for (int m = 16; m >= 1; m >>= 1) {
        sx += __shfl_xor(sx, m, 32);
        sy += __shfl_xor(sy, m, 32);
        sz += __shfl_xor(sz, m, 32);
#pragma unroll
        for (int h = 0; h < 3; ++h) {
            kmx[h] = fmaxf(kmx[h], __shfl_xor(kmx[h], m, 32));
            kmn[h] = fminf(kmn[h], __shfl_xor(kmn[h], m, 32));
        }
    }
    __syncthreads();   // k_s/v_s visible

    // attention output o[i,h], then @ wo + bo, then max over heads
    float o[3];
#pragma unroll
    for (int h = 0; h < 3; ++h) {
        const float qh = q[h];
        const float mrow = qh * (qh >= 0.f ? kmx[h] : kmn[h]);
        float den = 0.f, num = 0.f;
#pragma unroll
        for (int j = 0; j < 32; ++j) {
            float e = __expf(qh * k_s[h][j] - mrow);
            den += e;
            num += e * v_s[h][j];
        }
        o[h] = num / den;
    }
    float fa0 = o[0] * wo[0] + o[1] * wo[3] + o[2] * wo[6] + bo[0];
    float fa1 = o[0] * wo[1] + o[1] * wo[4] + o[2] * wo[7] + bo[1];
    float fa2 = o[0] * wo[2] + o[1] * wo[5] + o[2] * wo[8] + bo[2];
    float ma  = fmaxf(fa0, fmaxf(fa1, fa2));

    float sum_ma = ma;
#pragma unroll
    for (int m = 16; m >= 1; m >>= 1) sum_ma += __shfl_xor(sum_ma, m, 32);
    const float r = ma / sum_ma;

    const int npts = num_points[n];
    if (lane < 32) {
        r_s[i] = r;
        const float inv = 1.f / (float)npts;
        const float mx = sx * inv, my = sy * inv, mz = sz * inv;
        const int c1 = coors[4 * n + 1], c2 = coors[4 * n + 2], c3 = coors[4 * n + 3];
        const float cx = (float)c3 * VXc + XOFFc;
        const float cy = (float)c2 * VYc + YOFFc;
        const float cz = (float)c1 * VZc + ZOFFc;
        const bool valid = (i < npts);
        u_s[i][0] = valid ? f.x - cx : 0.f;
        u_s[i][1] = valid ? f.y - cy : 0.f;
        u_s[i][2] = valid ? f.z - cz : 0.f;
        u_s[i][3] = valid ? f.w      : 0.f;
        u_s[i][4] = valid ? f.x - mx : 0.f;
        u_s[i][5] = valid ? f.y - my : 0.f;
        u_s[i][6] = valid ? f.z - mz : 0.f;
    }
    __syncthreads();

    // step C: lane = channel c; all LDS reads are wave-uniform (broadcast)
    const int c = lane;
    float w7[7];
    w7[0] = pfn_w[0 * 64 + c] + pfn_w[7 * 64 + c];
    w7[1] = pfn_w[1 * 64 + c] + pfn_w[8 * 64 + c];
    w7[2] = pfn_w[2 * 64 + c] + pfn_w[9 * 64 + c];
    w7[3] = pfn_w[3 * 64 + c];
    w7[4] = pfn_w[4 * 64 + c];
    w7[5] = pfn_w[5 * 64 + c];
    w7[6] = pfn_w[6 * 64 + c];
    const float a = AB[c];
    const float b = AB[64 + c];

    float fm = -FLT_MAX, fav = -FLT_MAX;
#pragma unroll
    for (int ii = 0; ii < 32; ++ii) {
        float x = u_s[ii][0] * w7[0] + u_s[ii][1] * w7[1] + u_s[ii][2] * w7[2] +
                  u_s[ii][3] * w7[3] + u_s[ii][4] * w7[4] + u_s[ii][5] * w7[5] +
                  u_s[ii][6] * w7[6];
        float y = x * a + b;
        y = (y > 0.f) ? y : 0.01f * y;
        fm  = fmaxf(fm, y);
        fav = fmaxf(fav, r_s[ii] * y);
    }
    out[(size_t)n * 64 + c] = 0.5f * (fav + fm);
}

// ---------------------------------------------------------------------------
// Launch
// ---------------------------------------------------------------------------
extern "C" void kernel_launch(void* const* d_in, const int* in_sizes, int n_in,
                              void* d_out, int out_size, void* d_ws, size_t ws_size,
                              hipStream_t stream) {
    const float4* feats  = (const float4*)d_in[0];
    const int*    npts   = (const int*)d_in[1];
    const int*    coors  = (const int*)d_in[2];
    const float*  pfn_w  = (const float*)d_in[3];
    const float*  gamma  = (const float*)d_in[4];
    const float*  beta   = (const float*)d_in[5];
    const float*  wq     = (const float*)d_in[6];
    const float*  wk     = (const float*)d_in[7];
    const float*  wv     = (const float*)d_in[8];
    const float*  wo     = (const float*)d_in[9];
    const float*  bq     = (const float*)d_in[10];
    const float*  bk     = (const float*)d_in[11];
    const float*  bv     = (const float*)d_in[12];
    const float*  bo     = (const float*)d_in[13];
    float*        out    = (float*)d_out;

    double* S  = (double*)d_ws;                     // 35 doubles = 280 B
    float*  AB = (float*)((char*)d_ws + 280);       // 128 floats

    hipMemsetAsync(d_ws, 0, 280, stream);

    stats_kernel<<<(NP + 255) / 256, 256, 0, stream>>>(feats, npts, coors, S);
    affine_kernel<<<1, 64, 0, stream>>>(S, pfn_w, gamma, beta, AB);
    main_kernel<<<NP, 64, 0, stream>>>(feats, npts, coors, pfn_w, AB,
                                       wq, wk, wv, wo, bq, bk, bv, bo, out);
}

// Round 2
// 154.872 us; speedup vs baseline: 1.1081x; 1.1081x over previous
//
#include <hip/hip_runtime.h>
#include <float.h>
#include <math.h>

// Problem constants (from reference)
constexpr int NP = 30000;
constexpr int M  = 32;
constexpr float VXc = 0.2f, VYc = 0.2f, VZc = 4.0f;
constexpr float XOFFc = 0.1f, YOFFc = -39.9f, ZOFFc = -1.0f;

typedef __attribute__((ext_vector_type(8)))  short bf16x8;   // 8 bf16 in 4 VGPRs
typedef __attribute__((ext_vector_type(16))) float f32x16;   // MFMA 32x32 accumulator

// fp32 -> bf16 round-to-nearest-even (bit pattern)
__device__ __forceinline__ unsigned short f2bf(float x) {
    unsigned int u = __builtin_bit_cast(unsigned int, x);
    u = (u + 0x7fffu + ((u >> 16) & 1u)) >> 16;
    return (unsigned short)u;
}

// ---------------------------------------------------------------------------
// Kernel 1: global second-moment stats for BatchNorm.
// Thread per (pillar, point): grid-stride, coalesced float4 loads. Pillar
// means via width-32 shuffles (each pillar occupies one wave half). 35-term
// fp32 per-thread accumulators -> wave butterfly -> block LDS -> 35 double
// atomics per block (480 blocks -> negligible contention).
// ---------------------------------------------------------------------------
__global__ __launch_bounds__(256) void stats_kernel(
    const float4* __restrict__ fp,
    const int*    __restrict__ num_points,
    const int*    __restrict__ coors,
    double*       __restrict__ Sout)      // 35 doubles, pre-zeroed
{
    float S[35];
#pragma unroll
    for (int k = 0; k < 35; ++k) S[k] = 0.f;

    const int stride = gridDim.x * blockDim.x;
    const int base   = blockIdx.x * blockDim.x + threadIdx.x;

    for (int it = 0; it < 8; ++it) {
        const int p = base + it * stride;
        if (p >= NP * M) continue;       // wave-uniform (boundaries are x64)
        const int n = p >> 5;
        const int i = p & 31;
        const float4 f = fp[p];

        float sx = f.x, sy = f.y, sz = f.z;
#pragma unroll
        for (int m = 16; m >= 1; m >>= 1) {
            sx += __shfl_xor(sx, m, 32);
            sy += __shfl_xor(sy, m, 32);
            sz += __shfl_xor(sz, m, 32);
        }
        const int npts = num_points[n];
        const float inv = 1.f / (float)npts;
        const int c1 = coors[4 * n + 1], c2 = coors[4 * n + 2], c3 = coors[4 * n + 3];
        const float cx = (float)c3 * VXc + XOFFc;
        const float cy = (float)c2 * VYc + YOFFc;
        const float cz = (float)c1 * VZc + ZOFFc;
        const bool valid = (i < npts);

        float u[7];
        u[0] = valid ? f.x - cx : 0.f;
        u[1] = valid ? f.y - cy : 0.f;
        u[2] = valid ? f.z - cz : 0.f;
        u[3] = valid ? f.w      : 0.f;
        u[4] = valid ? f.x - sx * inv : 0.f;
        u[5] = valid ? f.y - sy * inv : 0.f;
        u[6] = valid ? f.z - sz * inv : 0.f;

#pragma unroll
        for (int k = 0; k < 7; ++k) S[k] += u[k];
        int idx = 7;
#pragma unroll
        for (int k = 0; k < 7; ++k)
#pragma unroll
            for (int l = k; l < 7; ++l)
                S[idx++] += u[k] * u[l];
    }

#pragma unroll
    for (int k = 0; k < 35; ++k) {
#pragma unroll
        for (int m = 32; m >= 1; m >>= 1) S[k] += __shfl_xor(S[k], m, 64);
    }

    __shared__ float part[4][35];
    const int wid = threadIdx.x >> 6, ln = threadIdx.x & 63;
    if (ln == 0) {
#pragma unroll
        for (int k = 0; k < 35; ++k) part[wid][k] = S[k];
    }
    __syncthreads();
    if (threadIdx.x < 35) {
        float t = part[0][threadIdx.x] + part[1][threadIdx.x] +
                  part[2][threadIdx.x] + part[3][threadIdx.x];
        atomicAdd(&Sout[threadIdx.x], (double)t);
    }
}

// ---------------------------------------------------------------------------
// Kernel 2: fold BN into affine y = a*x + b (double), and pre-pack the MFMA
// B-fragment: Wpk[(t*64+lane)*8 + j] = bf16(w7[k=half*8+j][n=(lane&31)+32t]),
// zero for half==1 lanes and j==7 (K padding).
// ---------------------------------------------------------------------------
__global__ __launch_bounds__(128) void affine_kernel(
    const double* __restrict__ S,       // 35
    const float*  __restrict__ pfn_w,   // (10,64)
    const float*  __restrict__ gamma,
    const float*  __restrict__ beta,
    float*        __restrict__ AB,      // A[64] then B[64]
    unsigned short* __restrict__ Wpk)   // 2*64*8 bf16
{
    const int tid = threadIdx.x;

    if (tid < 64) {
        const int c = tid;
        double w7[7];
        w7[0] = (double)pfn_w[0 * 64 + c] + (double)pfn_w[7 * 64 + c];
        w7[1] = (double)pfn_w[1 * 64 + c] + (double)pfn_w[8 * 64 + c];
        w7[2] = (double)pfn_w[2 * 64 + c] + (double)pfn_w[9 * 64 + c];
        w7[3] = (double)pfn_w[3 * 64 + c];
        w7[4] = (double)pfn_w[4 * 64 + c];
        w7[5] = (double)pfn_w[5 * 64 + c];
        w7[6] = (double)pfn_w[6 * 64 + c];

        const double invNM = 1.0 / ((double)NP * (double)M);
        double mean = 0.0;
#pragma unroll
        for (int k = 0; k < 7; ++k) mean += S[k] * w7[k];
        mean *= invNM;

        double ex2 = 0.0;
        int idx = 7;
#pragma unroll
        for (int k = 0; k < 7; ++k)
#pragma unroll
            for (int l = k; l < 7; ++l) {
                double t = S[idx++] * w7[k] * w7[l];
                ex2 += (k == l) ? t : 2.0 * t;
            }
        ex2 *= invNM;

        double var = ex2 - mean * mean;
        double a = (double)gamma[c] / sqrt(var + 1e-3);
        AB[c]      = (float)a;
        AB[64 + c] = (float)((double)beta[c] - mean * a);
    }

    // B fragment pack (tid = t*64 + lane)
    {
        const int l = tid & 63;
        const int t = tid >> 6;
        const int half = l >> 5;
        const int n = (l & 31) + 32 * t;
        unsigned short v[8] = {0, 0, 0, 0, 0, 0, 0, 0};
        if (half == 0) {
            float w7[7];
            w7[0] = pfn_w[0 * 64 + n] + pfn_w[7 * 64 + n];
            w7[1] = pfn_w[1 * 64 + n] + pfn_w[8 * 64 + n];
            w7[2] = pfn_w[2 * 64 + n] + pfn_w[9 * 64 + n];
            w7[3] = pfn_w[3 * 64 + n];
            w7[4] = pfn_w[4 * 64 + n];
            w7[5] = pfn_w[5 * 64 + n];
            w7[6] = pfn_w[6 * 64 + n];
#pragma unroll
            for (int j = 0; j < 7; ++j) v[j] = f2bf(w7[j]);
        }
#pragma unroll
        for (int j = 0; j < 8; ++j) Wpk[tid * 8 + j] = v[j];
    }
}

// ---------------------------------------------------------------------------
// Kernel 3: main. 256-thread blocks, one wave per pillar (4 pillars/block).
// Attention: rank-1 scores -> single-pass softmax; j-loop split across the
// two wave halves (48 exps/lane), combined with xor-32 shuffles.
// Step C (U[32x7] @ W7[7x64]) via 2x v_mfma_f32_32x32x16_bf16:
//   A[m=lane&31][k=(lane>>5)*8+j] = lane's own u (half-1 lanes zero),
//   B pre-packed in workspace, C/D row = (reg&3)+8*(reg>>2)+4*half.
// ---------------------------------------------------------------------------
__global__ __launch_bounds__(256) void main_kernel(
    const float4* __restrict__ fp,
    const int*    __restrict__ num_points,
    const int*    __restrict__ coors,
    const float*  __restrict__ AB,
    const unsigned short* __restrict__ Wpk,
    const float*  __restrict__ wq, const float* __restrict__ wk,
    const float*  __restrict__ wv, const float* __restrict__ wo,
    const float*  __restrict__ bq, const float* __restrict__ bk,
    const float*  __restrict__ bv, const float* __restrict__ bo,
    float*        __restrict__ out)
{
    const int tid  = threadIdx.x;
    const int pb   = tid >> 6;          // pillar within block
    const int lane = tid & 63;
    const int i    = lane & 31;
    const int half = lane >> 5;
    const int n    = blockIdx.x * 4 + pb;

    __shared__ float2 kv_s[4][3][32];
    __shared__ float  r_s[4][32];

    const float4 f = fp[(size_t)n * M + i];

    // q/k/v for this point (uniform weights -> scalar loads)
    float q[3], kk[3], vv[3];
#pragma unroll
    for (int h = 0; h < 3; ++h) {
        q[h]  = f.x * wq[0 * 3 + h] + f.y * wq[1 * 3 + h] + f.z * wq[2 * 3 + h] + bq[h];
        kk[h] = f.x * wk[0 * 3 + h] + f.y * wk[1 * 3 + h] + f.z * wk[2 * 3 + h] + bk[h];
        vv[h] = f.x * wv[0 * 3 + h] + f.y * wv[1 * 3 + h] + f.z * wv[2 * 3 + h] + bv[h];
    }
    if (half == 0) {
#pragma unroll
        for (int h = 0; h < 3; ++h) kv_s[pb][h][i] = make_float2(kk[h], vv[h]);
    }

    // width-32 butterflies: xyz sums + per-head k max/min
    float sx = f.x, sy = f.y, sz = f.z;
    float kmx[3], kmn[3];
#pragma unroll
    for (int h = 0; h < 3; ++h) { kmx[h] = kk[h]; kmn[h] = kk[h]; }
#pragma unroll
    for (int m = 16; m >= 1; m >>= 1) {
        sx += __shfl_xor(sx, m, 32);
        sy += __shfl_xor(sy, m, 32);
        sz += __shfl_xor(sz, m, 32);
#pragma unroll
        for (int h = 0; h < 3; ++h) {
            kmx[h] = fmaxf(kmx[h], __shfl_xor(kmx[h], m, 32));
            kmn[h] = fminf(kmn[h], __shfl_xor(kmn[h], m, 32));
        }
    }
    __syncthreads();   // kv_s visible

    // attention: each half sums 16 of the 32 j's, combine across halves
    const float LOG2E = 1.4426950408889634f;
    float num[3], den[3];
    const int j0 = half * 16;
#pragma unroll
    for (int h = 0; h < 3; ++h) {
        const float qh2  = q[h] * LOG2E;
        const float mrow = qh2 * (q[h] >= 0.f ? kmx[h] : kmn[h]);
        float d = 0.f, nu = 0.f;
#pragma unroll
        for (int jj = 0; jj < 16; ++jj) {
            float2 kv = kv_s[pb][h][j0 + jj];
            float e = exp2f(__builtin_fmaf(qh2, kv.x, -mrow));
            d  += e;
            nu += e * kv.y;
        }
        num[h] = nu; den[h] = d;
    }
#pragma unroll
    for (int h = 0; h < 3; ++h) {
        num[h] += __shfl_xor(num[h], 32, 64);
        den[h] += __shfl_xor(den[h], 32, 64);
    }
    float o0 = num[0] / den[0], o1 = num[1] / den[1], o2 = num[2] / den[2];

    float fa0 = o0 * wo[0] + o1 * wo[3] + o2 * wo[6] + bo[0];
    float fa1 = o0 * wo[1] + o1 * wo[4] + o2 * wo[7] + bo[1];
    float fa2 = o0 * wo[2] + o1 * wo[5] + o2 * wo[8] + bo[2];
    float ma  = fmaxf(fa0, fmaxf(fa1, fa2));

    float sum_ma = ma;
#pragma unroll
    for (int m = 16; m >= 1; m >>= 1) sum_ma += __shfl_xor(sum_ma, m, 32);
    const float r = ma / sum_ma;
    if (half == 0) r_s[pb][i] = r;

    // 7-dim features for this lane's point
    const int npts = num_points[n];
    const float inv = 1.f / (float)npts;
    const int c1 = coors[4 * n + 1], c2 = coors[4 * n + 2], c3 = coors[4 * n + 3];
    const float cx = (float)c3 * VXc + XOFFc;
    const float cy = (float)c2 * VYc + YOFFc;
    const float cz = (float)c1 * VZc + ZOFFc;
    const bool valid = (i < npts);

    float u[7];
    u[0] = valid ? f.x - cx : 0.f;
    u[1] = valid ? f.y - cy : 0.f;
    u[2] = valid ? f.z - cz : 0.f;
    u[3] = valid ? f.w      : 0.f;
    u[4] = valid ? f.x - sx * inv : 0.f;
    u[5] = valid ? f.y - sy * inv : 0.f;
    u[6] = valid ? f.z - sz * inv : 0.f;

    // A fragment: lane's own point, k = half*8 + j  (half 1 -> zeros)
    bf16x8 afr;
#pragma unroll
    for (int e = 0; e < 8; ++e) afr[e] = 0;
    if (half == 0) {
#pragma unroll
        for (int e = 0; e < 7; ++e) afr[e] = (short)f2bf(u[e]);
    }

    const bf16x8 bf0 = *reinterpret_cast<const bf16x8*>(Wpk + (size_t)lane * 8);
    const bf16x8 bf1 = *reinterpret_cast<const bf16x8*>(Wpk + (size_t)(64 + lane) * 8);

    f32x16 acc0, acc1;
#pragma unroll
    for (int e = 0; e < 16; ++e) { acc0[e] = 0.f; acc1[e] = 0.f; }
    acc0 = __builtin_amdgcn_mfma_f32_32x32x16_bf16(afr, bf0, acc0, 0, 0, 0);
    acc1 = __builtin_amdgcn_mfma_f32_32x32x16_bf16(afr, bf1, acc1, 0, 0, 0);

    __syncthreads();   // r_s visible

    // r for this lane's 16 rows (shared between the two channel tiles)
    float rv[16];
#pragma unroll
    for (int rg = 0; rg < 16; ++rg) {
        const int row = (rg & 3) + 8 * (rg >> 2) + 4 * half;
        rv[rg] = r_s[pb][row];
    }

    float res[2];
#pragma unroll
    for (int t = 0; t < 2; ++t) {
        const int c = (lane & 31) + 32 * t;
        const float a = AB[c];
        const float b = AB[64 + c];
        float fm = -FLT_MAX, fav = -FLT_MAX;
#pragma unroll
        for (int rg = 0; rg < 16; ++rg) {
            const float x = (t ? acc1[rg] : acc0[rg]);
            float y = __builtin_fmaf(x, a, b);
            y = fmaxf(y, 0.01f * y);            // leaky relu
            fm  = fmaxf(fm, y);
            fav = fmaxf(fav, rv[rg] * y);
        }
        fm  = fmaxf(fm,  __shfl_xor(fm,  32, 64));
        fav = fmaxf(fav, __shfl_xor(fav, 32, 64));
        res[t] = 0.5f * (fav + fm);
    }
    out[(size_t)n * 64 + half * 32 + (lane & 31)] = res[half];
}

// ---------------------------------------------------------------------------
// Launch
// ---------------------------------------------------------------------------
extern "C" void kernel_launch(void* const* d_in, const int* in_sizes, int n_in,
                              void* d_out, int out_size, void* d_ws, size_t ws_size,
                              hipStream_t stream) {
    const float4* feats  = (const float4*)d_in[0];
    const int*    npts   = (const int*)d_in[1];
    const int*    coors  = (const int*)d_in[2];
    const float*  pfn_w  = (const float*)d_in[3];
    const float*  gamma  = (const float*)d_in[4];
    const float*  beta   = (const float*)d_in[5];
    const float*  wq     = (const float*)d_in[6];
    const float*  wk     = (const float*)d_in[7];
    const float*  wv     = (const float*)d_in[8];
    const float*  wo     = (const float*)d_in[9];
    const float*  bq     = (const float*)d_in[10];
    const float*  bk     = (const float*)d_in[11];
    const float*  bv     = (const float*)d_in[12];
    const float*  bo     = (const float*)d_in[13];
    float*        out    = (float*)d_out;

    double*         S   = (double*)d_ws;                      // 35 doubles
    float*          AB  = (float*)((char*)d_ws + 384);        // 128 floats
    unsigned short* Wpk = (unsigned short*)((char*)d_ws + 896); // 1024 ushort

    hipMemsetAsync(d_ws, 0, 280, stream);

    stats_kernel<<<480, 256, 0, stream>>>(feats, npts, coors, S);
    affine_kernel<<<1, 128, 0, stream>>>(S, pfn_w, gamma, beta, AB, Wpk);
    main_kernel<<<NP / 4, 256, 0, stream>>>(feats, npts, coors, AB, Wpk,
                                            wq, wk, wv, wo, bq, bk, bv, bo, out);
}